// Round 4
// baseline (364.936 us; speedup 1.0000x reference)
//
#include <hip/hip_runtime.h>

// FloodPath R7: R5's small-state window + R6's wave-privacy + full occupancy.
//   K1 (pack): unchanged — stream float2 [H][W][2] -> occ/flood bit planes.
//   K2 (flood): each wave owns a 64x64 halo'd window in ONE u64/lane
//     (lane = row, funnel-shifted load), 16 shfl dilation steps, bit-sliced
//     counters (7 u64 persistent state => ~40 VGPR => 8 waves/SIMD).
//     Output stage is WAVE-PRIVATE: wave's 32x32 interior in 4 iterations
//     of 8 rows (lane -> row lane>>3, 4-px group lane&7). Zero __syncthreads;
//     wave-sync LDS via s_waitcnt lgkmcnt(0). out2 rows padded to 104 floats
//     (row offset = 8 banks) so staging writes are 2-way (free) not 8-way.
//     LDS 20.3 KB -> 8 blocks/CU, 32 waves/CU. Packed dwordx4 stores kept
//     (197 MB ideal write traffic, proven in R5).

typedef unsigned long long u64;

#define HH 4096
#define WW 4096
#define WPR 64            // u64 words per image row
#define NSTEPS 16
#define HALO 16
#define IT 32             // interior tile side per wave (64x64 window)

// ---------------- Kernel 1: bitpack ----------------
__global__ __launch_bounds__(256) void pack_kernel(
    const float* __restrict__ flood_input,
    u64* __restrict__ occP, u64* __restrict__ flP)
{
    const int lane = threadIdx.x & 63;
    const int wv   = threadIdx.x >> 6;
    const int r    = blockIdx.x;                  // one image row per block
#pragma unroll
    for (int b = 0; b < 2; ++b) {
        float vx[8], vy[8];
#pragma unroll
        for (int j = 0; j < 8; ++j) {
            const int w = wv * 16 + b * 8 + j;
            const float2 v = *(const float2*)(flood_input +
                                ((size_t)r * WW + (w << 6) + lane) * 2);
            vx[j] = v.x; vy[j] = v.y;
        }
#pragma unroll
        for (int j = 0; j < 8; ++j) {
            const int w = wv * 16 + b * 8 + j;
            const u64 om = __ballot(vx[j] > 0.5f);
            const u64 fm = __ballot(vy[j] > 0.5f);
            if (lane == 0) {
                occP[(size_t)r * WPR + w] = om;
                flP [(size_t)r * WPR + w] = fm;
            }
        }
    }
}

// ---------------- Kernel 2: flood + count + output ----------------
__global__ __launch_bounds__(256, 8) void flood_kernel(
    const u64* __restrict__ occP, const u64* __restrict__ flP,
    const float* __restrict__ flood_count,
    float* __restrict__ out)
{
    // wave-private transpose planes: [row][occ,f,c0..4] — 7168 B total
    __shared__ u64 plane[4][IT][7];
    // wave-private packed output staging: 8 rows x 104 floats (pad: 96->104
    // shifts each row by 8 banks; write pattern becomes 2-way). 13184 B.
    __shared__ float out2[4][7 * 104 + 96];

    const int tid  = threadIdx.x;
    const int lane = tid & 63;
    const int wv   = tid >> 6;

    const int tile_r0 = blockIdx.y * IT;                 // 0..4064
    const int tile_c0 = blockIdx.x * (4 * IT) + wv * IT; // wave's 32 cols

    // ---- Stage window: rows tile_r0-16+lane, cols tile_c0-16 .. +47.
    const int gr  = tile_r0 - HALO + lane;
    const bool rin = (gr >= 0) & (gr < HH);
    const int s   = tile_c0 - HALO;              // >= -16
    const int q0  = ((s + 64) >> 6) - 1;         // floor(s/64)
    const int sh  = s - (q0 << 6);               // 16 or 48

    const size_t base = (size_t)(rin ? gr : 0) * WPR;
    const int qa = min(max(q0, 0), WPR - 1);
    const int qb = min(max(q0 + 1, 0), WPR - 1);
    u64 o0 = occP[base + qa], o1 = occP[base + qb];
    u64 f0 = flP [base + qa], f1 = flP [base + qb];
    const bool va = rin & (q0 >= 0);
    const bool vb = rin & (q0 + 1 < WPR);
    if (!va) { o0 = ~0ull; f0 = 0ull; }          // OOB => wall, no flood
    if (!vb) { o1 = ~0ull; f1 = 0ull; }
    const u64 occ = (o0 >> sh) | (sh ? (o1 << (64 - sh)) : 0ull);
    u64       f   = (f0 >> sh) | (sh ? (f1 << (64 - sh)) : 0ull);

    // ---- 16 dilation steps, fully in registers. No barriers.
    const u64 nocc = ~occ;
    u64 c0 = 0, c1 = 0, c2 = 0, c3 = 0, c4 = 0;
#pragma unroll
    for (int it = 0; it < NSTEPS; ++it) {
        u64 up = __shfl_up(f, 1);
        u64 dn = __shfl_down(f, 1);
        if (lane == 0)  up = 0ull;
        if (lane == 63) dn = 0ull;
        f = nocc & (f | (f << 1) | (f >> 1) | up | dn);
        u64 c = f, t;
        t = c0; c0 = t ^ c; c = t & c;
        t = c1; c1 = t ^ c; c = t & c;
        t = c2; c2 = t ^ c; c = t & c;
        t = c3; c3 = t ^ c; c = t & c;
        c4 ^= c;                                 // max 16: no carry out
    }

    // ---- Wave-private transpose: lanes 16..47 hold interior rows.
    if (lane >= HALO && lane < HALO + IT) {
        u64* p = plane[wv][lane - HALO];
        p[0] = occ; p[1] = f;
        p[2] = c0; p[3] = c1; p[4] = c2; p[5] = c3; p[6] = c4;
    }
    asm volatile("s_waitcnt lgkmcnt(0)" ::: "memory");   // wave-sync LDS

    // ---- Output: 4 iterations x 8 rows, fully wave-private, no barriers.
    //   compute: lane -> row (lane>>3), 4-px group (lane&7); stage 12 floats;
    //   readback linearly; 3 packed dwordx4 stores per lane per iteration.
    const int rsub = lane >> 3;                  // 0..7: row within chunk
    const int g    = lane & 7;                   // 0..7: 4-px group in row
    const int bit0 = HALO + g * 4;
    for (int t = 0; t < 4; ++t) {
        const int irow = t * 8 + rsub;
        const int grr  = tile_r0 + irow;
        const float4 fc4 = *(const float4*)(flood_count +
                                (size_t)grr * WW + tile_c0 + g * 4);
        const u64* p = plane[wv][irow];
        const u64 ow = p[0], fw = p[1];
        const u64 k0 = p[2], k1 = p[3], k2 = p[4], k3 = p[5], k4 = p[6];

        float v[12];
        const float fcv[4] = { fc4.x, fc4.y, fc4.z, fc4.w };
#pragma unroll
        for (int j = 0; j < 4; ++j) {
            const int bit = bit0 + j;
            int cv = (int)((k0 >> bit) & 1ull)
                   + ((int)((k1 >> bit) & 1ull) << 1)
                   + ((int)((k2 >> bit) & 1ull) << 2)
                   + ((int)((k3 >> bit) & 1ull) << 3)
                   + ((int)((k4 >> bit) & 1ull) << 4);
            v[j*3+0] = (float)((ow >> bit) & 1ull);
            v[j*3+1] = (float)((fw >> bit) & 1ull);
            v[j*3+2] = (float)cv + fcv[j];
        }
        // stage: padded row stride 104 floats (416 B), 16B-aligned per lane
        float* dst = &out2[wv][rsub * 104 + g * 12];
        *(float4*)(dst + 0) = make_float4(v[0], v[1], v[2],  v[3]);
        *(float4*)(dst + 4) = make_float4(v[4], v[5], v[6],  v[7]);
        *(float4*)(dst + 8) = make_float4(v[8], v[9], v[10], v[11]);

        asm volatile("s_waitcnt lgkmcnt(0)" ::: "memory");   // wave-sync LDS

        // readback linearly (logical 8x96 floats), packed dwordx4 stores
#pragma unroll
        for (int st = 0; st < 3; ++st) {
            const int L   = st * 256 + lane * 4;   // 0..767 in 768-float chunk
            const int row = L / 96;                // 0..7 (magic-mul)
            const int off = L - row * 96;          // 0..95, multiple of 4
            const float4 q = *(const float4*)(&out2[wv][row * 104 + off]);
            *(float4*)(out + ((size_t)(tile_r0 + t * 8 + row) * WW
                              + tile_c0) * 3 + off) = q;
        }
    }
}

extern "C" void kernel_launch(void* const* d_in, const int* in_sizes, int n_in,
                              void* d_out, int out_size, void* d_ws, size_t ws_size,
                              hipStream_t stream) {
    const float* flood_input = (const float*)d_in[0];  // [4096][4096][2]
    const float* flood_cnt   = (const float*)d_in[1];  // [4096][4096]
    float* out = (float*)d_out;                        // [4096][4096][3]

    u64* occP = (u64*)d_ws;                            // 2 MiB
    u64* flP  = occP + (size_t)HH * WPR;               // 2 MiB

    pack_kernel<<<dim3(HH), dim3(256), 0, stream>>>(flood_input, occP, flP);

    dim3 grid(WW / (4 * IT), HH / IT);                 // 32 x 128 = 4096 blocks
    flood_kernel<<<grid, dim3(256), 0, stream>>>(occP, flP, flood_cnt, out);
}